// Round 3
// baseline (158.900 us; speedup 1.0000x reference)
//
#include <hip/hip_runtime.h>
#include <hip/hip_bf16.h>

typedef unsigned short u16;
typedef unsigned int u32;
typedef __attribute__((ext_vector_type(8))) short bf16x8;
typedef __attribute__((ext_vector_type(4))) float floatx4;

__device__ __forceinline__ u16 f2bf(float f){
    union{float f;u32 i;}v; v.f=f; u32 r=v.i+0x7FFFu+((v.i>>16)&1u); return (u16)(r>>16);
}
__device__ __forceinline__ float bf2f(u16 h){
    union{u32 i; float f;}v; v.i=(u32)h<<16; return v.f;
}
__device__ __forceinline__ u32 pkbf(float a, float b){
    union { __hip_bfloat162 h; u32 u; } cv;
    cv.h = __float22bfloat162_rn(float2{a, b});
    return cv.u;
}

#define DD 512
#define NTOK 128

// ---------------------------------------------------------------------------
// prep_t: LDS-free transpose+convert (R1/R2-verified, unchanged).
// ---------------------------------------------------------------------------
__global__ __launch_bounds__(512) void prep_t(
    const float* __restrict__ W1, const float* __restrict__ W2,
    u16* __restrict__ W1T, u16* __restrict__ W2T)
{
    const int bid = blockIdx.x;
    const float* src; u16* dst; int sstride, dstride, kt, ct;
    if (bid < 128) { kt = bid >> 3; ct = bid & 7;  src = W1; sstride = 512; dst = W1T; dstride = 1024; }
    else { int t = bid - 128; kt = t >> 2; ct = t & 3; src = W2; sstride = 256; dst = W2T; dstride = 512; }
    const int cl = threadIdx.x & 63;
    const int kchunk = (threadIdx.x >> 6) << 3;
    const int srow = kt * 64 + kchunk, scol = ct * 64 + cl;
    float v[8];
#pragma unroll
    for (int i = 0; i < 8; ++i) v[i] = src[(size_t)(srow + i) * sstride + scol];
    uint4 o = make_uint4(pkbf(v[0], v[1]), pkbf(v[2], v[3]),
                         pkbf(v[4], v[5]), pkbf(v[6], v[7]));
    *(uint4*)(dst + (size_t)scol * dstride + srow) = o;
}

// ---------------------------------------------------------------------------
// prep_g (R2-verified, unchanged): Hf = features @ [W1a|W1b], fp32 outputs.
// ---------------------------------------------------------------------------
__global__ __launch_bounds__(512) void prep_g(
    const float* __restrict__ features, const u16* __restrict__ W1T,
    const float* __restrict__ b1, float* __restrict__ Hf1b, float* __restrict__ Hf2)
{
    const int bM = blockIdx.x, bN = blockIdx.y;
    const int tid = threadIdx.x;
    const int wid = tid >> 6, lane = tid & 63, lrow = lane & 15, quad = lane >> 4;
    const int wm = wid >> 1, wn = wid & 1;
    __shared__ __align__(16) u16 At[64 * 64];
    __shared__ __align__(16) u16 Btl[64 * 64];

    floatx4 acc[2];
    acc[0] = (floatx4)(0.0f); acc[1] = (floatx4)(0.0f);

    const int m = tid >> 3, seg = tid & 7, sw = m & 7;
    const int zoff = (bN >> 3) * 512;
    const u16* bsrc_lane = W1T
        + (size_t)((bN & 7) * 64 + wid * 8 + (lane >> 3)) * 1024
        + zoff + (((lane & 7) ^ (lane >> 3)) << 3);

    for (int kc = 0; kc < 8; ++kc) {
        const int k0 = kc * 64;
        __builtin_amdgcn_global_load_lds(
            (const __attribute__((address_space(1))) u32*)(bsrc_lane + k0),
            (__attribute__((address_space(3))) u32*)(Btl + wid * 512), 16, 0, 0);
        {
            const float4* srcp = (const float4*)(features + (size_t)(bM * 64 + m) * DD + k0 + seg * 8);
            float4 f0 = srcp[0], f1 = srcp[1];
            *(uint4*)(At + m * 64 + ((seg ^ sw) << 3)) =
                make_uint4(pkbf(f0.x, f0.y), pkbf(f0.z, f0.w), pkbf(f1.x, f1.y), pkbf(f1.z, f1.w));
        }
        __syncthreads();
#pragma unroll
        for (int ks = 0; ks < 2; ++ks) {
            const int ch = ks * 4 + quad;
            int r = wm * 16 + lrow;
            bf16x8 afr = *(const bf16x8*)(At + r * 64 + ((ch ^ (r & 7)) << 3));
#pragma unroll
            for (int j = 0; j < 2; ++j) {
                int c = wn * 32 + j * 16 + lrow;
                bf16x8 bfr = *(const bf16x8*)(Btl + c * 64 + ((ch ^ (c & 7)) << 3));
                acc[j] = __builtin_amdgcn_mfma_f32_16x16x32_bf16(afr, bfr, acc[j], 0, 0, 0);
            }
        }
        __syncthreads();
    }
    float* outp = (bN >> 3) ? Hf2 : Hf1b;
#pragma unroll
    for (int j = 0; j < 2; ++j) {
        int col = (bN & 7) * 64 + wn * 32 + j * 16 + lrow;
        float bb = (bN >> 3) ? 0.0f : b1[col];
#pragma unroll
        for (int r = 0; r < 4; ++r) {
            int row = bM * 64 + wm * 16 + quad * 4 + r;
            outp[(size_t)row * DD + col] = acc[j][r] + bb;
        }
    }
}

// ---------------------------------------------------------------------------
// Fused main — R0 frame (sync structure, main GEMM, B-DMA untouched). New
// A-stage: H^T tiles via rank-5 MFMA. Per kc per wave:
//   a_frag[k][t] = [s1[k], c0[k], c0[k], c1[k], c1[k], 0,0,0]   (3 ds_read_u16)
//   pfrag[t][m]  = [1, px_hi, px_lo, py_hi, py_lo, 0,0,0]       (kc-invariant)
//   C            = hf2 fp32 fragment (1 dwordx4 per 16x16 tile, zero unpacks)
// px split into hi+lo bf16 -> bf16xbf16 products exact in fp32 (>= R0 precision).
// pfrag quads 1-3 zeroed once; a_frag garbage there multiplies zero.
// Atile writes: relu+cvt_pk -> ds_write_b64 at the same swizzled positions
// the (unchanged) main GEMM reads. Epilogue: packed cvt_pk on row-pairs.
// ---------------------------------------------------------------------------
__global__ __launch_bounds__(512) void fused_main(
    const float* __restrict__ Hf1b, const float* __restrict__ Hf2,
    const u16* __restrict__ W2T, const float* __restrict__ W1,
    const float* __restrict__ b2, const float* __restrict__ W3,
    const float* __restrict__ b3, const float* __restrict__ positions,
    float* __restrict__ out)
{
    const int b = blockIdx.x, n = blockIdx.y;     // b fastest -> XCD = b
    const int tid = threadIdx.x;
    const int base_bn = b * NTOK + n;
    const int wid = tid >> 6, lane = tid & 63, lrow = lane & 15, quad = lane >> 4;

    __shared__ __align__(16) u16 c0b[DD], c1b[DD], s1b[DD];  // bf16 coefs, 3 KB
    __shared__ __align__(16) u32 pbf[NTOK * 4];              // B' frags, 2 KB
    __shared__ __align__(16) u16 w3t[16 * 264];              // W3^T padded, 8.25 KB
    __shared__ __align__(16) char mbuf[49152];   // Atile 16K + Btile 32K | gh 34K
    u16* Atile = (u16*)mbuf;                     // [128][64] swizzled
    u16* Btile = (u16*)(mbuf + 16384);           // [256][64] swizzled
    u16* gh    = (u16*)mbuf;                     // [128][136] epilogue

    // ---- phase 0 ----
    {
        int k = tid;  // 512 threads == DD
        c0b[k] = f2bf(W1[(size_t)1024 * DD + k]);
        c1b[k] = f2bf(W1[(size_t)1025 * DD + k]);
        s1b[k] = f2bf(Hf1b[(size_t)base_bn * DD + k]);   // b1 already folded
    }
    {   // w3t: W3 (256x4 fp32) transposed, padded to 16 cols, bf16
        int c = tid & 15, kb2 = tid >> 4;          // kb2 0..31
        int k0w = kb2 * 8;
        u32 wv[4];
#pragma unroll
        for (int p = 0; p < 4; ++p) {
            int ka = k0w + p * 2;
            u16 va = (c < 4) ? f2bf(W3[ka * 4 + c])       : (u16)0;
            u16 vb = (c < 4) ? f2bf(W3[(ka + 1) * 4 + c]) : (u16)0;
            wv[p] = (u32)va | ((u32)vb << 16);
        }
        *(uint2*)(w3t + c * 264 + k0w)     = make_uint2(wv[0], wv[1]);
        *(uint2*)(w3t + c * 264 + k0w + 4) = make_uint2(wv[2], wv[3]);
    }
    if (tid < NTOK) {   // pbf: per-m B' fragment data [1, px_hi, px_lo, py_hi, py_lo]
        float pnx = positions[(size_t)base_bn * 2 + 0];
        float pny = positions[(size_t)base_bn * 2 + 1];
        float px = pnx - positions[(size_t)(b * NTOK + tid) * 2 + 0];
        float py = pny - positions[(size_t)(b * NTOK + tid) * 2 + 1];
        u16 ph = f2bf(px); u16 pl = f2bf(px - bf2f(ph));
        u16 qh = f2bf(py); u16 ql = f2bf(py - bf2f(qh));
        pbf[tid * 4 + 0] = 0x3F80u | ((u32)ph << 16);
        pbf[tid * 4 + 1] = (u32)pl | ((u32)qh << 16);
        pbf[tid * 4 + 2] = (u32)ql;
        pbf[tid * 4 + 3] = 0u;
    }
    // B-DMA lane source pointer (q-invariant swizzle, R8-proven)
    const int csrc = lane >> 3, wsrc = lane & 7;
    const u16* bsrc_lane = W2T + csrc * DD + ((wsrc ^ csrc) << 3);
    __syncthreads();

    // kc-invariant B' fragments (one per 16-row m-tile of this wave)
    bf16x8 pfrag[4];
#pragma unroll
    for (int j = 0; j < 4; ++j) {
        int mj = (wid >> 2) * 64 + j * 16 + lrow;
        union { uint4 u; bf16x8 v; } t;
        t.u = *(const uint4*)(pbf + mj * 4);
        if (quad != 0) t.u = make_uint4(0u, 0u, 0u, 0u);
        pfrag[j] = t.v;
    }

    const int wm = wid >> 2, wn = wid & 3;       // main GEMM 2x4 wave grid
    floatx4 acc[4][4];
#pragma unroll
    for (int i = 0; i < 4; ++i)
#pragma unroll
        for (int j = 0; j < 4; ++j) acc[i][j] = (floatx4)(0.0f);

    // A-stage invariants: wave (wid>>2) owns m-half, (wid&3) owns k-quarter
    const float* hrow = Hf2 + ((size_t)(b * NTOK) + (wid >> 2) * 64 + lrow) * DD
                        + (wid & 3) * 16 + quad * 4;
    const int kk0 = (wid & 3) * 16 + lrow;               // a_frag k index base
    const int aw_base = ((wid >> 2) * 64 + lrow) * 64;   // Atile u16 base (j=0)
    const int pch = (((wid & 3) * 2 + (quad >> 1)) ^ (lrow & 7)); // phys chunk (j-inv)
    const int aw_off = (pch << 3) + (quad & 1) * 4;

    // ---- K loop ----
    for (int kc = 0; kc < 8; ++kc) {
        const int k0 = kc * 64;
        // stage B via LDS-DMA first (zero data regs; latency hidden by A-stage)
#pragma unroll
        for (int q = 0; q < 4; ++q) {
            const int slot = wid * 4 + q;        // wave-uniform
            __builtin_amdgcn_global_load_lds(
                (const __attribute__((address_space(1))) u32*)(bsrc_lane + slot * 8 * DD + k0),
                (__attribute__((address_space(3))) u32*)(Btile + slot * 512), 16, 0, 0);
        }

        {   // A-stage: H^T tiles = mfma(a_frag, pfrag_j, hf2_frag), relu, cvt, b64 write
            int idx = k0 + kk0;
            u32 sv = s1b[idx], c0v = c0b[idx], c1v = c1b[idx];
            union { u32 u[4]; bf16x8 v; } af;
            af.u[0] = sv | (c0v << 16);
            af.u[1] = c0v | (c1v << 16);
            af.u[2] = c1v;
            af.u[3] = 0u;
#pragma unroll
            for (int j = 0; j < 4; ++j) {
                floatx4 hc = *(const floatx4*)(hrow + (size_t)j * 16 * DD + k0);
                floatx4 hv = __builtin_amdgcn_mfma_f32_16x16x32_bf16(af.v, pfrag[j], hc, 0, 0, 0);
                u32 p0 = pkbf(fmaxf(hv[0], 0.0f), fmaxf(hv[1], 0.0f));
                u32 p1 = pkbf(fmaxf(hv[2], 0.0f), fmaxf(hv[3], 0.0f));
                *(uint2*)(Atile + aw_base + j * 1024 + aw_off) = make_uint2(p0, p1);
            }
        }
        __syncthreads();   // vmcnt(0)+lgkmcnt(0) drain: Atile and B-DMA ready
#pragma unroll
        for (int ks = 0; ks < 2; ++ks) {
            const int ch = ks * 4 + quad;
            bf16x8 afr[4], bfr[4];
#pragma unroll
            for (int i = 0; i < 4; ++i) {
                int r = wm * 64 + i * 16 + lrow;
                afr[i] = *(const bf16x8*)(Atile + r * 64 + ((ch ^ (r & 7)) << 3));
            }
#pragma unroll
            for (int j = 0; j < 4; ++j) {
                int c = wn * 64 + j * 16 + lrow;
                bfr[j] = *(const bf16x8*)(Btile + c * 64 + ((ch ^ (c & 7)) << 3));
            }
#pragma unroll
            for (int i = 0; i < 4; ++i)
#pragma unroll
                for (int j = 0; j < 4; ++j)
                    acc[i][j] = __builtin_amdgcn_mfma_f32_16x16x32_bf16(afr[i], bfr[j], acc[i][j], 0, 0, 0);
        }
        __syncthreads();
    }

    // ---- epilogue: relu(acc+b2) -> gh bf16 (packed cvt) -> layer-3 MFMA ----
    float b2v[4];
#pragma unroll
    for (int j = 0; j < 4; ++j) b2v[j] = b2[wn * 64 + j * 16 + lrow];

    const int smrow = wid * 16;                  // per-wave epilogue row block
    floatx4 acc3 = (floatx4)(0.0f);
#pragma unroll
    for (int half = 0; half < 2; ++half) {
        __syncthreads();
        if ((wn >> 1) == half) {
#pragma unroll
            for (int i = 0; i < 4; ++i)
#pragma unroll
                for (int j = 0; j < 4; ++j)
#pragma unroll
                    for (int r = 0; r < 4; r += 2) {
                        int row0 = wm * 64 + i * 16 + quad * 4 + r;
                        int col = (wn & 1) * 64 + j * 16 + lrow;
                        float v0 = fmaxf(acc[i][j][r]     + b2v[j], 0.0f);
                        float v1 = fmaxf(acc[i][j][r + 1] + b2v[j], 0.0f);
                        u32 pk = pkbf(v0, v1);
                        gh[row0 * 136 + col]       = (u16)pk;
                        gh[(row0 + 1) * 136 + col] = (u16)(pk >> 16);
                    }
        }
        __syncthreads();
#pragma unroll
        for (int ks = 0; ks < 4; ++ks) {
            bf16x8 gfrag = *(const bf16x8*)(gh + (smrow + lrow) * 136 + ks * 32 + quad * 8);
            bf16x8 wfrag = *(const bf16x8*)(w3t + lrow * 264 + half * 128 + ks * 32 + quad * 8);
            acc3 = __builtin_amdgcn_mfma_f32_16x16x32_bf16(gfrag, wfrag, acc3, 0, 0, 0);
        }
    }
    if (lrow < 4) {
        float bo = b3[lrow];
#pragma unroll
        for (int r = 0; r < 4; ++r) {
            int row = smrow + quad * 4 + r;
            out[(size_t)base_bn * 512 + row * 4 + lrow] = acc3[r] + bo;
        }
    }
}

// ---------------------------------------------------------------------------
extern "C" void kernel_launch(void* const* d_in, const int* in_sizes, int n_in,
                              void* d_out, int out_size, void* d_ws, size_t ws_size,
                              hipStream_t stream)
{
    const float* features  = (const float*)d_in[0];
    const float* positions = (const float*)d_in[1];
    const float* W1 = (const float*)d_in[2];
    const float* b1 = (const float*)d_in[3];
    const float* W2 = (const float*)d_in[4];
    const float* b2 = (const float*)d_in[5];
    const float* W3 = (const float*)d_in[6];
    const float* b3 = (const float*)d_in[7];
    float* out = (float*)d_out;

    char* ws = (char*)d_ws;
    u16*   W2T  = (u16*)(ws);                  // 256*512*2  = 262144 B
    u16*   W1T  = (u16*)(ws + 262144);         // 512*1024*2 = 1048576 B
    float* Hf1b = (float*)(ws + 1310720);      // 1024*512*4 = 2097152 B
    float* Hf2  = (float*)(ws + 3407872);      // 1024*512*4 = 2097152 B (total 5.25 MB)

    prep_t<<<dim3(160), 512, 0, stream>>>(W1, W2, W1T, W2T);
    prep_g<<<dim3(16, 16), 512, 0, stream>>>(features, W1T, b1, Hf1b, Hf2);
    fused_main<<<dim3(8, 128), 512, 0, stream>>>(Hf1b, Hf2, W2T, W1, b2, W3, b3,
                                                 positions, out);
}

// Round 4
// 128.662 us; speedup vs baseline: 1.2350x; 1.2350x over previous
//
#include <hip/hip_runtime.h>
#include <hip/hip_bf16.h>

typedef unsigned short u16;
typedef unsigned int u32;
typedef __attribute__((ext_vector_type(8))) short bf16x8;
typedef __attribute__((ext_vector_type(4))) float floatx4;

__device__ __forceinline__ float bflo(u32 u){ union{u32 i; float f;}v; v.i=u<<16; return v.f; }
__device__ __forceinline__ float bfhi(u32 u){ union{u32 i; float f;}v; v.i=u&0xFFFF0000u; return v.f; }
__device__ __forceinline__ u16 f2bf(float f){
    union{float f;u32 i;}v; v.f=f; u32 r=v.i+0x7FFFu+((v.i>>16)&1u); return (u16)(r>>16);
}
__device__ __forceinline__ u32 pkbf(float a, float b){
    union { __hip_bfloat162 h; u32 u; } cv;
    cv.h = __float22bfloat162_rn(float2{a, b});
    return cv.u;
}

#define DD 512
#define NTOK 128

// ---------------------------------------------------------------------------
// prep_k: grid (16,8,3), 512 thr.  (R0-proven, byte-identical)
// ---------------------------------------------------------------------------
__global__ __launch_bounds__(512) void prep_k(
    const float* __restrict__ features, const float* __restrict__ W1,
    const float* __restrict__ W2, const float* __restrict__ b1,
    u16* __restrict__ Hf1b, u16* __restrict__ Hf2, u16* __restrict__ W2T)
{
    const int z = blockIdx.z;
    const int tid = threadIdx.x;

    if (z == 2) {   // W2 transpose
        __shared__ u16 tile[32][33];
        const int tx = tid & 31, ty = tid >> 5;      // ty 0..15
        const int r0 = blockIdx.x * 32, c0 = blockIdx.y * 32;
#pragma unroll
        for (int i = 0; i < 2; ++i) {
            int r = ty + i * 16;
            tile[r][tx] = f2bf(W2[(size_t)(r0 + r) * 256 + (c0 + tx)]);
        }
        __syncthreads();
#pragma unroll
        for (int i = 0; i < 2; ++i) {
            int c = ty + i * 16;
            W2T[(size_t)(c0 + c) * 512 + (r0 + tx)] = tile[tx][c];
        }
        return;
    }

    const int bM = blockIdx.x, bN = blockIdx.y;
    u16* outp = z ? Hf2 : Hf1b;
    __shared__ __align__(16) u16 At[64 * 64];
    __shared__ __align__(16) u16 Btl[64 * 64];
    const int wid = tid >> 6, lane = tid & 63, lrow = lane & 15, quad = lane >> 4;
    const int wm = wid >> 1, wn = wid & 1;

    floatx4 acc[2];
    acc[0] = (floatx4)(0.0f); acc[1] = (floatx4)(0.0f);

    const int m = tid >> 3, seg = tid & 7, sw = m & 7;      // A staging map
    const int kr = tid >> 3, csB = tid & 7;                 // B staging map

    for (int kc = 0; kc < 8; ++kc) {
        const int k0 = kc * 64;
        {   // stage A: 8 fp32 -> 8 bf16, one uint4, XOR-swizzled
            const float4* src = (const float4*)(features + (size_t)(bM * 64 + m) * DD + k0 + seg * 8);
            float4 f0 = src[0], f1 = src[1];
            *(uint4*)(At + m * 64 + ((seg ^ sw) << 3)) =
                make_uint4(pkbf(f0.x, f0.y), pkbf(f0.z, f0.w), pkbf(f1.x, f1.y), pkbf(f1.z, f1.w));
        }
        {   // stage B from W1 rows (transpose-in-write, swizzled scalar b16)
            const float4* src = (const float4*)(W1 + (size_t)(z * 512 + k0 + kr) * DD + bN * 64 + csB * 8);
            float4 g0 = src[0], g1 = src[1];
            float f[8] = { g0.x, g0.y, g0.z, g0.w, g1.x, g1.y, g1.z, g1.w };
            const int chunkB = (kr >> 3), offB = kr & 7;
#pragma unroll
            for (int i = 0; i < 8; ++i) {
                int c = csB * 8 + i;                        // c & 7 == i
                Btl[c * 64 + ((chunkB ^ i) << 3) + offB] = f2bf(f[i]);
            }
        }
        __syncthreads();
#pragma unroll
        for (int ks = 0; ks < 2; ++ks) {
            const int ch = ks * 4 + quad;
            int r = wm * 16 + lrow;
            bf16x8 afr = *(const bf16x8*)(At + r * 64 + ((ch ^ (r & 7)) << 3));
#pragma unroll
            for (int j = 0; j < 2; ++j) {
                int c = wn * 32 + j * 16 + lrow;
                bf16x8 bfr = *(const bf16x8*)(Btl + c * 64 + ((ch ^ (c & 7)) << 3));
                acc[j] = __builtin_amdgcn_mfma_f32_16x16x32_bf16(afr, bfr, acc[j], 0, 0, 0);
            }
        }
        __syncthreads();
    }
#pragma unroll
    for (int j = 0; j < 2; ++j) {
        int col = bN * 64 + wn * 32 + j * 16 + lrow;
        float bb = z ? 0.0f : b1[col];
#pragma unroll
        for (int r = 0; r < 4; ++r) {
            int row = bM * 64 + wm * 16 + quad * 4 + r;
            outp[(size_t)row * DD + col] = f2bf(acc[j][r] + bb);
        }
    }
}

// ---------------------------------------------------------------------------
// Fused main — exact R0 body (proven 56.3 us, VGPR=64) with ONE change:
// w3t moved from its own static LDS into mbuf+34816 (Btile is dead after the
// K loop; gh occupies only [0,34816) of mbuf) and filled after the K loop.
// Static LDS 60.9K -> 52.2K  =>  3 blocks/CU instead of 2, so co-resident
// blocks cover each other's per-kc vmcnt(0) barrier drains (the 27% idle).
// ---------------------------------------------------------------------------
__global__ __launch_bounds__(512) void fused_main(
    const u16* __restrict__ Hf1b, const u16* __restrict__ Hf2,
    const u16* __restrict__ W2T, const float* __restrict__ W1,
    const float* __restrict__ b2, const float* __restrict__ W3,
    const float* __restrict__ b3, const float* __restrict__ positions,
    float* __restrict__ out)
{
    const int b = blockIdx.x, n = blockIdx.y;     // b fastest -> XCD = b
    const int tid = threadIdx.x;
    const int base_bn = b * NTOK + n;
    const int wid = tid >> 6, lane = tid & 63, lrow = lane & 15, quad = lane >> 4;

    __shared__ __align__(16) u16 c0b[DD], c1b[DD], s1b[DD];  // bf16 coefs, 3 KB
    __shared__ __align__(16) char mbuf[49152];   // Atile 16K + Btile 32K | gh 34K + w3t 8.25K
    u16* Atile = (u16*)mbuf;                     // [128][64] swizzled
    u16* Btile = (u16*)(mbuf + 16384);           // [256][64] swizzled
    u16* gh    = (u16*)mbuf;                     // [128][136] epilogue
    u16* w3t   = (u16*)(mbuf + 34816);           // W3^T padded [16][264], epilogue-only

    // ---- phase 0 ----
    {
        int k = tid;  // 512 threads == DD
        c0b[k] = f2bf(W1[(size_t)1024 * DD + k]);
        c1b[k] = f2bf(W1[(size_t)1025 * DD + k]);
        s1b[k] = Hf1b[(size_t)base_bn * DD + k];   // b1 already folded
    }
    const int mrow = tid >> 2, seg = tid & 3, swA = mrow & 7;
    float px, py;
    {
        float pnx = positions[(size_t)base_bn * 2 + 0];
        float pny = positions[(size_t)base_bn * 2 + 1];
        px = pnx - positions[(size_t)(b * NTOK + mrow) * 2 + 0];
        py = pny - positions[(size_t)(b * NTOK + mrow) * 2 + 1];
    }
    // B-DMA lane source pointer: q-invariant swizzle (R0-proven)
    const int csrc = lane >> 3, wsrc = lane & 7;
    const u16* bsrc_lane = W2T + csrc * DD + ((wsrc ^ csrc) << 3);
    __syncthreads();

    const int wm = wid >> 2, wn = wid & 3;       // main GEMM 2x4 wave grid
    floatx4 acc[4][4];
#pragma unroll
    for (int i = 0; i < 4; ++i)
#pragma unroll
        for (int j = 0; j < 4; ++j) acc[i][j] = (floatx4)(0.0f);

    const u16* hf2p = Hf2 + (size_t)(b * NTOK + mrow) * DD;

    // ---- K loop (byte-identical to R0) ----
    for (int kc = 0; kc < 8; ++kc) {
        const int k0 = kc * 64;
        // stage B via LDS-DMA first (zero data regs; latency hidden by stage-A)
#pragma unroll
        for (int q = 0; q < 4; ++q) {
            const int slot = wid * 4 + q;        // wave-uniform
            __builtin_amdgcn_global_load_lds(
                (const __attribute__((address_space(1))) u32*)(bsrc_lane + slot * 8 * DD + k0),
                (__attribute__((address_space(3))) u32*)(Btile + slot * 512), 16, 0, 0);
        }

        const int kb = k0 + seg * 16;
        {   // stage A: h = relu(hf2 + s1 + px*c0 + py*c1), 16 elems/thread
            uint4 hv = *(const uint4*)(hf2p + kb);
            uint4 hw = *(const uint4*)(hf2p + kb + 8);
            uint4 sv = *(const uint4*)(s1b + kb);
            uint4 sw2 = *(const uint4*)(s1b + kb + 8);
            uint4 av = *(const uint4*)(c0b + kb);
            uint4 aw = *(const uint4*)(c0b + kb + 8);
            uint4 bv = *(const uint4*)(c1b + kb);
            uint4 bw = *(const uint4*)(c1b + kb + 8);
            auto hp = [&](u32 h, u32 s, u32 ca, u32 cb) -> u32 {
                float h0 = bflo(h) + bflo(s) + px * bflo(ca) + py * bflo(cb);
                float h1 = bfhi(h) + bfhi(s) + px * bfhi(ca) + py * bfhi(cb);
                return pkbf(fmaxf(h0, 0.0f), fmaxf(h1, 0.0f));
            };
            uint4 o0 = make_uint4(hp(hv.x, sv.x, av.x, bv.x), hp(hv.y, sv.y, av.y, bv.y),
                                  hp(hv.z, sv.z, av.z, bv.z), hp(hv.w, sv.w, av.w, bv.w));
            uint4 o1 = make_uint4(hp(hw.x, sw2.x, aw.x, bw.x), hp(hw.y, sw2.y, aw.y, bw.y),
                                  hp(hw.z, sw2.z, aw.z, bw.z), hp(hw.w, sw2.w, aw.w, bw.w));
            *(uint4*)(Atile + mrow * 64 + (((seg * 2    ) ^ swA) << 3)) = o0;
            *(uint4*)(Atile + mrow * 64 + (((seg * 2 + 1) ^ swA) << 3)) = o1;
        }
        __syncthreads();   // vmcnt(0)+lgkmcnt(0) drain: Atile and B-DMA ready
#pragma unroll
        for (int ks = 0; ks < 2; ++ks) {
            const int ch = ks * 4 + quad;
            bf16x8 afr[4], bfr[4];
#pragma unroll
            for (int i = 0; i < 4; ++i) {
                int r = wm * 64 + i * 16 + lrow;
                afr[i] = *(const bf16x8*)(Atile + r * 64 + ((ch ^ (r & 7)) << 3));
            }
#pragma unroll
            for (int j = 0; j < 4; ++j) {
                int c = wn * 64 + j * 16 + lrow;
                bfr[j] = *(const bf16x8*)(Btile + c * 64 + ((ch ^ (c & 7)) << 3));
            }
#pragma unroll
            for (int i = 0; i < 4; ++i)
#pragma unroll
                for (int j = 0; j < 4; ++j)
                    acc[i][j] = __builtin_amdgcn_mfma_f32_16x16x32_bf16(afr[i], bfr[j], acc[i][j], 0, 0, 0);
        }
        __syncthreads();
    }

    // ---- w3t fill (moved here from phase 0; Btile region now dead) ----
    {   // w3t: W3 (256x4 fp32) transposed, padded to 16 cols, bf16
        int c = tid & 15, kb2 = tid >> 4;          // kb2 0..31
        int k0w = kb2 * 8;
        u32 wv[4];
#pragma unroll
        for (int p = 0; p < 4; ++p) {
            int ka = k0w + p * 2;
            u16 va = (c < 4) ? f2bf(W3[ka * 4 + c])       : (u16)0;
            u16 vb = (c < 4) ? f2bf(W3[(ka + 1) * 4 + c]) : (u16)0;
            wv[p] = (u32)va | ((u32)vb << 16);
        }
        *(uint2*)(w3t + c * 264 + k0w)     = make_uint2(wv[0], wv[1]);
        *(uint2*)(w3t + c * 264 + k0w + 4) = make_uint2(wv[2], wv[3]);
    }

    // ---- epilogue: relu(acc+b2) -> gh bf16 halves -> layer-3 MFMA (R0) ----
    float b2v[4];
#pragma unroll
    for (int j = 0; j < 4; ++j) b2v[j] = b2[wn * 64 + j * 16 + lrow];

    const int smrow = wid * 16;                  // per-wave epilogue row block
    floatx4 acc3 = (floatx4)(0.0f);
#pragma unroll
    for (int half = 0; half < 2; ++half) {
        __syncthreads();
        if ((wn >> 1) == half) {
#pragma unroll
            for (int i = 0; i < 4; ++i)
#pragma unroll
                for (int j = 0; j < 4; ++j)
#pragma unroll
                    for (int r = 0; r < 4; ++r) {
                        int row = wm * 64 + i * 16 + quad * 4 + r;
                        int col = (wn & 1) * 64 + j * 16 + lrow;
                        gh[row * 136 + col] = f2bf(fmaxf(acc[i][j][r] + b2v[j], 0.0f));
                    }
        }
        __syncthreads();
#pragma unroll
        for (int ks = 0; ks < 4; ++ks) {
            bf16x8 gfrag = *(const bf16x8*)(gh + (smrow + lrow) * 136 + ks * 32 + quad * 8);
            bf16x8 wfrag = *(const bf16x8*)(w3t + lrow * 264 + half * 128 + ks * 32 + quad * 8);
            acc3 = __builtin_amdgcn_mfma_f32_16x16x32_bf16(gfrag, wfrag, acc3, 0, 0, 0);
        }
    }
    if (lrow < 4) {
        float bo = b3[lrow];
#pragma unroll
        for (int r = 0; r < 4; ++r) {
            int row = smrow + quad * 4 + r;
            out[(size_t)base_bn * 512 + row * 4 + lrow] = acc3[r] + bo;
        }
    }
}

// ---------------------------------------------------------------------------
extern "C" void kernel_launch(void* const* d_in, const int* in_sizes, int n_in,
                              void* d_out, int out_size, void* d_ws, size_t ws_size,
                              hipStream_t stream)
{
    const float* features  = (const float*)d_in[0];
    const float* positions = (const float*)d_in[1];
    const float* W1 = (const float*)d_in[2];
    const float* b1 = (const float*)d_in[3];
    const float* W2 = (const float*)d_in[4];
    const float* b2 = (const float*)d_in[5];
    const float* W3 = (const float*)d_in[6];
    const float* b3 = (const float*)d_in[7];
    float* out = (float*)d_out;

    char* ws = (char*)d_ws;
    u16* W2T  = (u16*)(ws);                 // 256*512*2 = 262144 B
    u16* Hf1b = (u16*)(ws + 262144);        // 1048576 B
    u16* Hf2  = (u16*)(ws + 1310720);       // 1048576 B (total 2.25 MB)

    prep_k<<<dim3(16, 8, 3), 512, 0, stream>>>(features, W1, W2, b1, Hf1b, Hf2, W2T);
    fused_main<<<dim3(8, 128), 512, 0, stream>>>(Hf1b, Hf2, W2T, W1, b2, W3, b3,
                                                 positions, out);
}